// Round 6
// baseline (312.594 us; speedup 1.0000x reference)
//
#include <hip/hip_runtime.h>
#include <hip/hip_bf16.h>
#include <stdint.h>

// VQ: x [N=131072, D=64] fp32, E [D=64, K=1024] fp32.
// R6 = R5 (verified bf16-MFMA hi/lo screen, exact-f64 refine) with:
//  - 32 rows/wave (2 row-tiles share B frags)  -> B L2 traffic 2.1 GB -> 1.05 GB
//  - single chained C per row-tile + fmed3 top2 -> epilogue 7 -> 4 VALU/elem
//  - refine fused into the screen block (LDS flag list) -> 2 kernels total
// Verified layouts (m89/m91/m120, R5-passed): A[m=lane&15][k=(lane>>4)*8+j],
// C/D col(code)=lane&15, row(x-row)=(lane>>4)*4+reg.

typedef unsigned long long u64;
typedef short short8 __attribute__((ext_vector_type(8)));
typedef float f32x4 __attribute__((ext_vector_type(4)));

constexpr int D = 64;
constexpr int K = 1024;
constexpr int XS = 72;           // LDS row stride in bf16 elems (144 B)
constexpr float TAU = 1e-3f;     // screen err ~1.5e-4 << TAU (R5-proven margin)

__device__ __forceinline__ unsigned short bf16_rne(float v) {
    uint32_t u = __float_as_uint(v);
    uint32_t r = u + 0x7FFFu + ((u >> 16) & 1u);
    return (unsigned short)(r >> 16);
}
__device__ __forceinline__ float bf16_f(unsigned short h) {
    return __uint_as_float(((uint32_t)h) << 16);
}
__device__ __forceinline__ uint32_t fmap(float v) {
    uint32_t u = __float_as_uint(v);
    return (u & 0x80000000u) ? ~u : (u | 0x80000000u);
}
__device__ __forceinline__ float funmap(uint32_t m) {
    uint32_t u = (m & 0x80000000u) ? (m ^ 0x80000000u) : ~m;
    return __uint_as_float(u);
}
__device__ __forceinline__ void top2_merge(u64& b, u64& s, u64 ob, u64 os) {
    if (ob < b) { s = (b < os) ? b : os; b = ob; }
    else        { s = (ob < s) ? ob : s; }
}
__device__ __forceinline__ u64 shfl_xor_u64(u64 v, int m) {
    uint32_t lo = (uint32_t)v, hi = (uint32_t)(v >> 32);
    lo = (uint32_t)__shfl_xor((int)lo, m, 64);
    hi = (uint32_t)__shfl_xor((int)hi, m, 64);
    return ((u64)hi << 32) | lo;
}
__device__ __forceinline__ double shfl_xor_f64(double v, int m) {
    int lo = __double2loint(v), hi = __double2hiint(v);
    lo = __shfl_xor(lo, m, 64);
    hi = __shfl_xor(hi, m, 64);
    return __hiloint2double(hi, lo);
}

// ---- prep: e_sq (f64/f32), ET[k][d] gather table, Bhi/Blo fragment-linear
//      bf16 tables of -2E (hi + residual lo). grid 256 x 256. (R5-proven) ----
__global__ __launch_bounds__(256) void vq_prep(const float* __restrict__ E,
                                               double* __restrict__ e_sq64,
                                               float* __restrict__ e_sq32,
                                               float* __restrict__ ET,
                                               unsigned short* __restrict__ Bhi,
                                               unsigned short* __restrict__ Blo) {
    int tid = blockIdx.x * 256 + threadIdx.x;        // 0..65535
    if (tid < K) {
        int k = tid;
        double s = 0.0;
        for (int d = 0; d < D; ++d) {
            float v = E[d * K + k];
            s = fma((double)v, (double)v, s);
            ET[k * D + d] = v;
        }
        e_sq64[k] = s;
        e_sq32[k] = (float)s;
    }
    // frag f = t*2+c, lane l, slot j: value=-2E[d][code], d=32c+8(l>>4)+j, code=16t+(l&15)
    {
        int j = tid & 7;
        int l = (tid >> 3) & 63;
        int f = tid >> 9;
        int c = f & 1;
        int t = f >> 1;
        int d = 32 * c + 8 * (l >> 4) + j;
        int code = 16 * t + (l & 15);
        float v = -2.0f * E[d * K + code];
        unsigned short h = bf16_rne(v);
        Bhi[tid] = h;
        Blo[tid] = bf16_rne(v - bf16_f(h));
    }
}

// ---- screen + fused refine: block = 128 rows (4 waves x 32), all 1024 codes ----
__global__ __launch_bounds__(256, 3) void vq_screen(
    const float* __restrict__ x, const float* __restrict__ E,
    const short8* __restrict__ Bh, const short8* __restrict__ Bl,
    const float* __restrict__ e_sq32, const double* __restrict__ e_sq64,
    const float* __restrict__ ET, float* __restrict__ out) {
    __shared__ unsigned short xhi[128 * XS];   // 18.4 KB
    __shared__ unsigned short xlo[128 * XS];   // 18.4 KB
    __shared__ float esq[K];                   // 4 KB
    __shared__ int bk[128];
    __shared__ int lcount;
    __shared__ int llist[128];
    __shared__ double xs[D];
    __shared__ double wbv[4];
    __shared__ int wbk[4];
    __shared__ int bks;

    const int t0 = threadIdx.x;
    const int base = blockIdx.x * 128;

    if (t0 == 0) lcount = 0;
    #pragma unroll
    for (int i = 0; i < 4; ++i) esq[i * 256 + t0] = e_sq32[i * 256 + t0];

    // stage x, split bf16 hi+lo (R5-proven body, 2 iterations for 128 rows)
    #pragma unroll
    for (int it = 0; it < 2; ++it) {
        int idx = it * 256 + t0;            // 0..511
        int row = idx >> 2, seg = idx & 3;
        const float4* xp = (const float4*)(x + (size_t)(base + row) * D + seg * 16);
        short8 H0, H1, L0, L1;
        #pragma unroll
        for (int q = 0; q < 4; ++q) {
            float4 v = xp[q];
            float vv[4] = {v.x, v.y, v.z, v.w};
            #pragma unroll
            for (int e = 0; e < 4; ++e) {
                unsigned short h = bf16_rne(vv[e]);
                unsigned short lo = bf16_rne(vv[e] - bf16_f(h));
                int p = q * 4 + e;
                if (p < 8) { H0[p] = (short)h; L0[p] = (short)lo; }
                else       { H1[p - 8] = (short)h; L1[p - 8] = (short)lo; }
            }
        }
        int off = row * XS + seg * 16;
        *(short8*)&xhi[off] = H0;  *(short8*)&xhi[off + 8] = H1;
        *(short8*)&xlo[off] = L0;  *(short8*)&xlo[off + 8] = L1;
    }
    __syncthreads();

    const int wid = t0 >> 6, l = t0 & 63;
    const int col = l & 15, quad = l >> 4;

    // A fragments for 2 row-tiles (verified layout)
    const int ra = wid * 32 + col;       // row-tile a
    const int rb = ra + 16;              // row-tile b
    short8 Ah0a = *(const short8*)&xhi[ra * XS + quad * 8];
    short8 Ah1a = *(const short8*)&xhi[ra * XS + 32 + quad * 8];
    short8 Al0a = *(const short8*)&xlo[ra * XS + quad * 8];
    short8 Al1a = *(const short8*)&xlo[ra * XS + 32 + quad * 8];
    short8 Ah0b = *(const short8*)&xhi[rb * XS + quad * 8];
    short8 Ah1b = *(const short8*)&xhi[rb * XS + 32 + quad * 8];
    short8 Al0b = *(const short8*)&xlo[rb * XS + quad * 8];
    short8 Al1b = *(const short8*)&xlo[rb * XS + 32 + quad * 8];

    float best[2][4], sec[2][4];
    int bidx[2][4];
    #pragma unroll
    for (int rt = 0; rt < 2; ++rt)
        #pragma unroll
        for (int r = 0; r < 4; ++r) { best[rt][r] = 3.4e38f; sec[rt][r] = 3.4e38f; bidx[rt][r] = 0; }

    short8 bh0 = Bh[l], bh1 = Bh[64 + l];
    short8 bl0 = Bl[l], bl1 = Bl[64 + l];

    for (int t = 0; t < 64; ++t) {
        int fb = ((t + 1) & 63) * 128 + l;        // prefetch next tile (t=63 wraps, unused)
        short8 nh0 = Bh[fb], nh1 = Bh[fb + 64];
        short8 nl0 = Bl[fb], nl1 = Bl[fb + 64];

        float esv = esq[t * 16 + col];
        f32x4 Ca = {esv, esv, esv, esv};
        f32x4 Cb = {esv, esv, esv, esv};
        Ca = __builtin_amdgcn_mfma_f32_16x16x32_bf16(Ah0a, bh0, Ca, 0, 0, 0);
        Cb = __builtin_amdgcn_mfma_f32_16x16x32_bf16(Ah0b, bh0, Cb, 0, 0, 0);
        Ca = __builtin_amdgcn_mfma_f32_16x16x32_bf16(Ah1a, bh1, Ca, 0, 0, 0);
        Cb = __builtin_amdgcn_mfma_f32_16x16x32_bf16(Ah1b, bh1, Cb, 0, 0, 0);
        Ca = __builtin_amdgcn_mfma_f32_16x16x32_bf16(Ah0a, bl0, Ca, 0, 0, 0);
        Cb = __builtin_amdgcn_mfma_f32_16x16x32_bf16(Ah0b, bl0, Cb, 0, 0, 0);
        Ca = __builtin_amdgcn_mfma_f32_16x16x32_bf16(Ah1a, bl1, Ca, 0, 0, 0);
        Cb = __builtin_amdgcn_mfma_f32_16x16x32_bf16(Ah1b, bl1, Cb, 0, 0, 0);
        Ca = __builtin_amdgcn_mfma_f32_16x16x32_bf16(Al0a, bh0, Ca, 0, 0, 0);
        Cb = __builtin_amdgcn_mfma_f32_16x16x32_bf16(Al0b, bh0, Cb, 0, 0, 0);
        Ca = __builtin_amdgcn_mfma_f32_16x16x32_bf16(Al1a, bh1, Ca, 0, 0, 0);
        Cb = __builtin_amdgcn_mfma_f32_16x16x32_bf16(Al1b, bh1, Cb, 0, 0, 0);

        int tc = t * 16;
        #pragma unroll
        for (int r = 0; r < 4; ++r) {
            float va = Ca[r];
            bool lta = va < best[0][r];
            sec[0][r]  = __builtin_amdgcn_fmed3f(va, best[0][r], sec[0][r]);
            best[0][r] = fminf(va, best[0][r]);
            bidx[0][r] = lta ? tc : bidx[0][r];
            float vb = Cb[r];
            bool ltb = vb < best[1][r];
            sec[1][r]  = __builtin_amdgcn_fmed3f(vb, best[1][r], sec[1][r]);
            best[1][r] = fminf(vb, best[1][r]);
            bidx[1][r] = ltb ? tc : bidx[1][r];
        }
        bh0 = nh0; bh1 = nh1; bl0 = nl0; bl1 = nl1;
    }

    // cross-lane top2 merge (masks 8..1 keep quad), flag ambiguous rows locally
    #pragma unroll
    for (int rt = 0; rt < 2; ++rt) {
        #pragma unroll
        for (int r = 0; r < 4; ++r) {
            u64 b = ((u64)fmap(best[rt][r]) << 32) | (uint32_t)(bidx[rt][r] + col);
            u64 s = ((u64)fmap(sec[rt][r]) << 32) | 0xFFFFFFFFu;
            #pragma unroll
            for (int m = 8; m >= 1; m >>= 1) {
                u64 ob = shfl_xor_u64(b, m);
                u64 os = shfl_xor_u64(s, m);
                top2_merge(b, s, ob, os);
            }
            if (col == 0) {
                int rowL = wid * 32 + rt * 16 + quad * 4 + r;   // verified C row map
                bk[rowL] = (int)(uint32_t)(b & 0xFFFFFFFFu);
                float vb = funmap((uint32_t)(b >> 32));
                float vs = funmap((uint32_t)(s >> 32));
                if (vs - vb < TAU) {
                    int idx = atomicAdd(&lcount, 1);
                    llist[idx] = rowL;                           // cap 128 = all rows
                }
            }
        }
    }
    __syncthreads();

    // gather: 16 floats per thread-seg, 2 iterations for 128 rows
    #pragma unroll
    for (int it = 0; it < 2; ++it) {
        int idx = it * 256 + t0;
        int row = idx >> 2, seg = idx & 3;
        const float4* ep = (const float4*)(ET + (size_t)bk[row] * D + seg * 16);
        float4* op = (float4*)(out + (size_t)(base + row) * D + seg * 16);
        op[0] = ep[0]; op[1] = ep[1]; op[2] = ep[2]; op[3] = ep[3];
    }
    __syncthreads();

    // fused refine: exact fp64 argmin for this block's flagged rows (R2/R3-proven body)
    int nf = lcount;
    for (int i = 0; i < nf; ++i) {
        int row = base + llist[i];
        if (t0 < D) xs[t0] = (double)x[(size_t)row * D + t0];
        __syncthreads();
        double bv = 1.0e300; int bkk = 0;
        #pragma unroll
        for (int j = 0; j < 4; ++j) {
            int k = t0 * 4 + j;
            double a = 0.0;
            for (int d = 0; d < D; ++d)
                a = fma(xs[d], (double)E[d * K + k], a);
            double v = fma(-2.0, a, e_sq64[k]);
            if (v < bv) { bv = v; bkk = k; }
        }
        #pragma unroll
        for (int m = 32; m >= 1; m >>= 1) {
            double ov = shfl_xor_f64(bv, m);
            int    ok = __shfl_xor(bkk, m, 64);
            if (ov < bv || (ov == bv && ok < bkk)) { bv = ov; bkk = ok; }
        }
        if ((t0 & 63) == 0) { wbv[t0 >> 6] = bv; wbk[t0 >> 6] = bkk; }
        __syncthreads();
        if (t0 == 0) {
            double b0 = wbv[0]; int k0 = wbk[0];
            for (int w = 1; w < 4; ++w)
                if (wbv[w] < b0 || (wbv[w] == b0 && wbk[w] < k0)) { b0 = wbv[w]; k0 = wbk[w]; }
            bks = k0;
        }
        __syncthreads();
        if (t0 < D) out[(size_t)row * D + t0] = ET[(size_t)bks * D + t0];
        __syncthreads();
    }
}

extern "C" void kernel_launch(void* const* d_in, const int* in_sizes, int n_in,
                              void* d_out, int out_size, void* d_ws, size_t ws_size,
                              hipStream_t stream) {
    const float* x = (const float*)d_in[0];
    const float* E = (const float*)d_in[1];
    float* out = (float*)d_out;
    int N = in_sizes[0] / D;   // 131072

    // ws: e_sq64 8K | e_sq32 4K | ET 256K | Bhi 128K | Blo 128K
    char* w = (char*)d_ws;
    double*         e_sq64 = (double*)w;          w += K * sizeof(double);
    float*          e_sq32 = (float*)w;           w += K * sizeof(float);
    float*          ET     = (float*)w;           w += (size_t)K * D * sizeof(float);
    unsigned short* Bhi    = (unsigned short*)w;  w += (size_t)K * D * sizeof(unsigned short);
    unsigned short* Blo    = (unsigned short*)w;

    vq_prep<<<256, 256, 0, stream>>>(E, e_sq64, e_sq32, ET, Bhi, Blo);
    vq_screen<<<N / 128, 256, 0, stream>>>(x, E, (const short8*)Bhi, (const short8*)Blo,
                                           e_sq32, e_sq64, ET, out);
}